// Round 6
// baseline (574.417 us; speedup 1.0000x reference)
//
#include <hip/hip_runtime.h>
#include <hip/hip_bf16.h>
#include <hip/hip_fp16.h>
#include <stdint.h>

// C=1024, K=64, H=1024. u_hat = x @ W^T as GEMM [65536,1024]x[1024,1024]^T.
// Pure-fp16 MFMA (R5-verified absmax 1.46e-3 < 2.99e-3). u_hat stored fp16.
// Routing: 1 block/c, u_hat[c] staged in LDS (128 KB), low-VGPR (R5's
// register-resident version cost ~290 µs vs ~25 µs roofline).

typedef _Float16 f16x8 __attribute__((ext_vector_type(8)));
typedef __attribute__((ext_vector_type(4))) float f32x4;

// ---------------- W fp32 -> fp16 ----------------
__global__ void wconv_kernel(const float* __restrict__ W, __half* __restrict__ Wh) {
    int i = blockIdx.x * blockDim.x + threadIdx.x;   // 262144 float4s
    float4 v = reinterpret_cast<const float4*>(W)[i];
    __half h0 = __float2half(v.x), h1 = __float2half(v.y);
    __half h2 = __float2half(v.z), h3 = __float2half(v.w);
    ushort4 o;
    o.x = *(unsigned short*)&h0; o.y = *(unsigned short*)&h1;
    o.z = *(unsigned short*)&h2; o.w = *(unsigned short*)&h3;
    reinterpret_cast<ushort4*>(Wh)[i] = o;
}

// ---------------- GEMM: fp16, 128x128 tile, BK=64, 4 waves (2x2) — unchanged from R5 ----------------
__global__ __launch_bounds__(256, 2) void gemm_kernel(const float* __restrict__ A,
                                                      const __half* __restrict__ B,
                                                      __half* __restrict__ U) {
    __shared__ __align__(16) __half As[128 * 64];
    __shared__ __align__(16) __half Bs[128 * 64];

    int bid = blockIdx.x;                       // 4096 blocks
    int swz = (bid & 7) * 512 + (bid >> 3);     // XCD-aware, bijective (4096 % 8 == 0)
    int bm = swz >> 3;                          // 512 row-panels
    int bn = swz & 7;                           // 8 col-panels
    int t = threadIdx.x;
    int lane = t & 63;
    int w = t >> 6;
    int wm = w >> 1, wn = w & 1;

    f32x4 acc[4][4];
#pragma unroll
    for (int i = 0; i < 4; ++i)
#pragma unroll
        for (int j = 0; j < 4; ++j) acc[i][j] = (f32x4){0.f, 0.f, 0.f, 0.f};

    const size_t arow0 = (size_t)bm * 128;

    for (int kt = 0; kt < 1024; kt += 64) {
        // stage A: 128x64 fp32 -> fp16. 8192 fp32 = 8 iters x 256 threads x 4
#pragma unroll
        for (int j = 0; j < 8; ++j) {
            int off = (j * 256 + t) * 4;
            int r = off >> 6, cc = off & 63;
            float4 v = *reinterpret_cast<const float4*>(&A[(arow0 + r) * 1024 + kt + cc]);
            __half h0 = __float2half(v.x), h1 = __float2half(v.y);
            __half h2 = __float2half(v.z), h3 = __float2half(v.w);
            ushort4 o;
            o.x = *(unsigned short*)&h0; o.y = *(unsigned short*)&h1;
            o.z = *(unsigned short*)&h2; o.w = *(unsigned short*)&h3;
            *reinterpret_cast<ushort4*>(&As[r * 64 + cc]) = o;
        }
        // stage B: 128x64 fp16. 8192 halfs = 4 iters x 256 threads x 8
#pragma unroll
        for (int j = 0; j < 4; ++j) {
            int off = (j * 256 + t) * 8;
            int r = off >> 6, cc = off & 63;
            uint4 v = *reinterpret_cast<const uint4*>(&B[((size_t)(bn * 128 + r)) * 1024 + kt + cc]);
            *reinterpret_cast<uint4*>(&Bs[r * 64 + cc]) = v;
        }
        __syncthreads();
#pragma unroll
        for (int kk = 0; kk < 2; ++kk) {
            int krow = kk * 32 + (lane >> 4) * 8;
            f16x8 af[4], bfv[4];
#pragma unroll
            for (int i = 0; i < 4; ++i) {
                af[i]  = *reinterpret_cast<const f16x8*>(&As[(wm * 64 + i * 16 + (lane & 15)) * 64 + krow]);
                bfv[i] = *reinterpret_cast<const f16x8*>(&Bs[(wn * 64 + i * 16 + (lane & 15)) * 64 + krow]);
            }
#pragma unroll
            for (int i = 0; i < 4; ++i)
#pragma unroll
                for (int j = 0; j < 4; ++j)
                    acc[i][j] = __builtin_amdgcn_mfma_f32_16x16x32_f16(af[i], bfv[j], acc[i][j], 0, 0, 0);
        }
        __syncthreads();
    }

    // epilogue: C/D layout col=lane&15, row=(lane>>4)*4+reg (m89-verified, dtype-indep)
    int c0 = bn * 128 + wn * 64 + (lane & 15);
    int r0 = bm * 128 + wm * 64 + (lane >> 4) * 4;
#pragma unroll
    for (int i = 0; i < 4; ++i)
#pragma unroll
        for (int j = 0; j < 4; ++j)
#pragma unroll
            for (int rr = 0; rr < 4; ++rr) {
                size_t row = (size_t)(r0 + i * 16 + rr);
                size_t col = (size_t)(c0 + j * 16);
                U[row * 1024 + col] = __float2half(acc[i][j][rr]);
            }
}

// ---------------- routing: 1 block per c, u_hat[c] in LDS (128 KB) ----------------
// 512 threads (8 waves); thread t owns h-pair (2t, 2t+1).
// b-update: wave w owns k = 8w..8w+7; c broadcast via c_s; one 6-shuffle reduce per k.
__global__ __launch_bounds__(512, 1) void route_kernel(const __half* __restrict__ U,
                                                       float* __restrict__ out) {
    __shared__ __align__(16) __half u_s[64 * 1024];   // 128 KB
    __shared__ float2 c_s[512];                        // 4 KB
    __shared__ float b_s[64];
    __shared__ float d_s[64];
    __shared__ float red_s[8];
    __shared__ float scale_s;

    const int c = blockIdx.x;
    const int t = threadIdx.x;
    const int lane = t & 63, w = t >> 6;

    // stage u_hat[c] -> LDS: linear coalesced copy, 16 x uint4 per thread
    const uint4* gsrc = reinterpret_cast<const uint4*>(U + (size_t)c * 65536);
    uint4* ls = reinterpret_cast<uint4*>(u_s);
#pragma unroll
    for (int m = 0; m < 16; ++m) ls[m * 512 + t] = gsrc[m * 512 + t];

    if (t < 64) b_s[t] = 0.0f;
    __syncthreads();

    float c0 = 0.f, c1 = 0.f;
    for (int it = 0; it < 3; ++it) {
        // softmax over K=64 (wave 0)
        if (t < 64) {
            float v = b_s[t];
            float m = v;
#pragma unroll
            for (int s = 32; s > 0; s >>= 1) m = fmaxf(m, __shfl_xor(m, s));
            float e = expf(v - m);
            float sum = e;
#pragma unroll
            for (int s = 32; s > 0; s >>= 1) sum += __shfl_xor(sum, s);
            d_s[t] = e / sum;
        }
        __syncthreads();

        // c_hat[h] = sum_k d[k]*u[k,h] ; u from LDS (b32 @ 4t: 2-way bank alias = free)
        float ch0 = 0.f, ch1 = 0.f;
#pragma unroll
        for (int k = 0; k < 64; ++k) {
            float dk = d_s[k];
            __half2 uv2 = *reinterpret_cast<const __half2*>(&u_s[k * 1024 + 2 * t]);
            float2 uv = __half22float2(uv2);
            ch0 = fmaf(dk, uv.x, ch0);
            ch1 = fmaf(dk, uv.y, ch1);
        }

        // squared norm over H (block reduction)
        float p = ch0 * ch0 + ch1 * ch1;
#pragma unroll
        for (int s = 32; s > 0; s >>= 1) p += __shfl_xor(p, s);
        if (lane == 0) red_s[w] = p;
        __syncthreads();
        if (t == 0) {
            float nrm = 0.f;
#pragma unroll
            for (int i = 0; i < 8; ++i) nrm += red_s[i];
            scale_s = sqrtf(nrm) / (1.0f + nrm);   // squash scale
        }
        __syncthreads();
        float sc = scale_s;
        c0 = sc * ch0;
        c1 = sc * ch1;
        if (it == 2) break;

        // publish c, then b[k] += sum_h u[k,h]*c[h]
        c_s[t] = (float2){c0, c1};
        __syncthreads();

        float cr0[8], cr1[8];
#pragma unroll
        for (int m = 0; m < 8; ++m) {
            float2 cc = c_s[lane + 64 * m];
            cr0[m] = cc.x; cr1[m] = cc.y;
        }
#pragma unroll
        for (int kk = 0; kk < 8; ++kk) {
            int k = w * 8 + kk;
            float s = 0.f;
#pragma unroll
            for (int m = 0; m < 8; ++m) {
                __half2 uv2 = *reinterpret_cast<const __half2*>(&u_s[k * 1024 + 2 * (lane + 64 * m)]);
                float2 uv = __half22float2(uv2);
                s = fmaf(cr0[m], uv.x, s);
                s = fmaf(cr1[m], uv.y, s);
            }
#pragma unroll
            for (int sh = 32; sh > 0; sh >>= 1) s += __shfl_xor(s, sh);
            if (lane == 0) b_s[k] += s;    // each k owned by exactly one wave
        }
        __syncthreads();
    }

    float2 o2; o2.x = c0; o2.y = c1;
    *reinterpret_cast<float2*>(&out[(size_t)c * 1024 + 2 * t]) = o2;
}

extern "C" void kernel_launch(void* const* d_in, const int* in_sizes, int n_in,
                              void* d_out, int out_size, void* d_ws, size_t ws_size,
                              hipStream_t stream) {
    const float* x = (const float*)d_in[0];        // [1024,64,1024] fp32
    const float* W = (const float*)d_in[1];        // [1024,1024] fp32
    float* out = (float*)d_out;                    // [1024,1024] fp32

    char* ws = (char*)d_ws;
    __half* Wh = (__half*)ws;                      // 2 MB
    __half* U  = (__half*)(ws + 2u * 1024 * 1024); // 128 MB fp16

    wconv_kernel<<<1024, 256, 0, stream>>>(W, Wh);
    gemm_kernel<<<4096, 256, 0, stream>>>(x, Wh, U);
    route_kernel<<<1024, 512, 0, stream>>>(U, out);
}